// Round 1
// baseline (540.925 us; speedup 1.0000x reference)
//
#include <hip/hip_runtime.h>
#include <stdint.h>

typedef unsigned short u16;
using short8 = __attribute__((ext_vector_type(8))) short;   // 8 bf16 (4 VGPRs)
using f32x4  = __attribute__((ext_vector_type(4))) float;   // 4 fp32 acc

#define T_LEN  4096
#define NTILE  16          // T tiles per batch row
#define TILE   256
#define HALO   8
#define COLS   272         // TILE + 2*HALO
#define ZSTR   40          // bf16 stride for z buffers (80B rows: 16B-aligned, 2-way banks)
#define ZROWS  274         // COLS + 2 guard cols
#define GSTR   168         // bf16 stride for B-matrix (336B rows)

__device__ __forceinline__ u16 f2bf(float f){
  uint32_t u = __builtin_bit_cast(uint32_t, f);
  u = u + 0x7fffu + ((u >> 16) & 1u);     // RNE
  return (u16)(u >> 16);
}
__device__ __forceinline__ float bf2f(u16 h){
  uint32_t u = ((uint32_t)h) << 16;
  return __builtin_bit_cast(float, u);
}

// ---------------------------------------------------------------------------
// K0: pack bf16 MFMA A-fragments for proj ([pf_w | id_w], 128x160) and conv
// weights (4 layers x 2 m-tiles x 3 taps, each 32x32). k-map: k = 8*(l>>4)+j.
// ---------------------------------------------------------------------------
__global__ void prep_kernel(const float* __restrict__ w3,
                            const float* __restrict__ pf_w,
                            const float* __restrict__ id_w,
                            u16* __restrict__ projA, u16* __restrict__ convA)
{
  int idx = blockIdx.x * 256 + threadIdx.x;
  if (idx < 8*5*64*8){                          // proj fragments
    int j = idx & 7, l = (idx >> 3) & 63, frag = idx >> 9;
    int kt = frag % 5, mt = frag / 5;
    int row = mt*16 + (l & 15);
    int k   = kt*32 + (l >> 4)*8 + j;
    float v = 0.f;
    if (row < 125){
      if (k < 125) v = pf_w[row*125 + k];
      else if (k >= 128 && k < 138) v = id_w[row*10 + (k - 128)];
    }
    projA[idx] = f2bf(v);
  } else {                                      // conv fragments
    int x = idx - 8*5*64*8;
    if (x < 4*2*3*64*8){
      int j = x & 7, l = (x >> 3) & 63, frag = x >> 9;
      int tap = frag % 3, mt = (frag / 3) & 1, lay = frag / 6;
      int m = mt*16 + (l & 15);
      int k = (l >> 4)*8 + j;
      float v = 0.f;
      if (m < 25 && k < 25) v = w3[((lay*25 + m)*25 + k)*3 + tap];
      convA[x] = f2bf(v);
    }
  }
}

// ---------------------------------------------------------------------------
// PASS 1: conv recursion -> per-(b,tile) channel sums (avg numerator).
// PASS 2: conv recursion -> gated B-matrix in LDS -> MFMA GEMM (proj+identity)
//         -> final BN + ReLU -> per-(b,tile) pooled sums.
// ---------------------------------------------------------------------------
template<int PASS>
__global__ __launch_bounds__(256)
void pass_kernel(const float* __restrict__ lfg,
                 const float* __restrict__ w1,  const float* __restrict__ b1,
                 const float* __restrict__ b3,
                 const float* __restrict__ bn_g, const float* __restrict__ bn_b,
                 const float* __restrict__ bn_m, const float* __restrict__ bn_v,
                 const u16*  __restrict__ convA, const u16* __restrict__ projA,
                 const float* __restrict__ gatews,
                 const float* __restrict__ pf_b, const float* __restrict__ id_b,
                 const float* __restrict__ fbn_g, const float* __restrict__ fbn_b,
                 const float* __restrict__ fbn_m, const float* __restrict__ fbn_v,
                 float* __restrict__ outpart)
{
  __shared__ __align__(16) u16 zbuf[2][ZROWS*ZSTR];
  __shared__ float lfs[10][COLS];
  __shared__ __align__(16) u16 glT[(PASS==2) ? 256*GSTR : 16];
  __shared__ float abn[32], cbn[32], w1s[32][2], b1s[32];
  __shared__ float accC[128];
  __shared__ float g5[5];
  __shared__ float Af[128], Bf[128];

  const int tid  = threadIdx.x;
  const int lane = tid & 63;
  const int wv   = tid >> 6;
  const int b    = blockIdx.y;
  const int tblk = blockIdx.x;
  const int t0   = tblk * TILE;

  // ---- init ----
  for (int x = tid; x < ZROWS*ZSTR; x += 256){ zbuf[0][x] = 0; zbuf[1][x] = 0; }
  for (int x = tid; x < 10*COLS; x += 256){
    int c = x / COLS, u = x % COLS;
    int t = t0 - HALO + u;
    lfs[c][u] = ((unsigned)t < (unsigned)T_LEN) ? lfg[(b*10 + c)*T_LEN + t] : 0.f;
  }
  if (tid < 128) accC[tid] = 0.f;
  if (tid < 32){                              // layer-4 BN (k=1 conv path)
    float a = 0.f, c = 0.f;
    if (tid < 25){
      float g = bn_g[4*25+tid], bb = bn_b[4*25+tid], m = bn_m[4*25+tid], v = bn_v[4*25+tid];
      a = g * rsqrtf(v + 1e-5f);
      c = bb - m*a;
    }
    abn[tid] = a; cbn[tid] = c;
  }
  if constexpr (PASS == 2){
    for (int x = tid; x < 256*GSTR; x += 256) glT[x] = 0;
    if (tid < 5) g5[tid] = gatews[b*5 + tid];
    if (tid < 128){
      float fs = 0.f, fsh = 0.f;
      if (tid < 125){
        fs  = fbn_g[tid] * rsqrtf(fbn_v[tid] + 1e-5f);
        fsh = (pf_b[tid] + id_b[tid] - fbn_m[tid])*fs + fbn_b[tid];
      }
      Af[tid] = fs; Bf[tid] = fsh;
    }
  }
  __syncthreads();

  // ---- build z3 = xs3 + y4 into zbuf[0]; handle y4 (c = 100..124) ----
  {
    const int w2 = tid & 31;
    const int ch = tid >> 5;
    const bool wok = (w2 < 25);
    float w40=0,w41=0,bb4=0,w30=0,w31=0,bb3=0;
    if (wok){
      w40 = w1[(4*25+w2)*2+0]; w41 = w1[(4*25+w2)*2+1]; bb4 = b1[4*25+w2];
      w30 = w1[(3*25+w2)*2+0]; w31 = w1[(3*25+w2)*2+1]; bb3 = b1[3*25+w2];
    }
    const float a4 = abn[w2], c4 = cbn[w2];
    float s4 = 0.f;
    for (int u = ch; u < COLS; u += 8){
      int t = t0 - HALO + u;
      bool tok = (unsigned)t < (unsigned)T_LEN;
      float xs4 = bb4 + w40*lfs[8][u] + w41*lfs[9][u];
      float y4  = fmaxf(xs4*a4 + c4, 0.f);
      float xs3 = bb3 + w30*lfs[6][u] + w31*lfs[7][u];
      float z3  = (tok && wok) ? (xs3 + y4) : 0.f;
      zbuf[0][(u+1)*ZSTR + w2] = f2bf(z3);
      bool interior = (u >= HALO) && (u < HALO + TILE);
      if (tok && interior && wok){
        if constexpr (PASS == 1) s4 += y4;
        if constexpr (PASS == 2) glT[(u - HALO)*GSTR + 100 + w2] = f2bf(y4 * g5[4]);
      }
    }
    if constexpr (PASS == 1){
      if (wok) atomicAdd(&accC[100 + w2], s4);
    }
  }
  if constexpr (PASS == 2){                  // identity rows (k = 128..137)
    for (int x = tid; x < 10*TILE; x += 256){
      int c = x >> 8, n = x & 255;
      glT[n*GSTR + 128 + c] = f2bf(lfs[c][n + HALO]);
    }
  }
  __syncthreads();

  // ---- conv layers i = 3..0 (MFMA, 2 m-tiles x 3 taps) ----
  u16* zin  = zbuf[0];
  u16* zout = zbuf[1];
  float ysum[8];
  #pragma unroll
  for (int q = 0; q < 8; ++q) ysum[q] = 0.f;

  for (int i = 3; i >= 0; --i){
    if (tid < 32){
      float a = 0.f, c = 0.f;
      if (tid < 25){
        float g = bn_g[i*25+tid], bb = bn_b[i*25+tid], m = bn_m[i*25+tid], v = bn_v[i*25+tid];
        a = g * rsqrtf(v + 1e-5f);
        c = (b3[i*25+tid] - m)*a + bb;     // conv bias folded into BN shift
      }
      abn[tid] = a; cbn[tid] = c;
      float q0=0,q1=0,qb=0;
      if (i > 0 && tid < 25){
        q0 = w1[((i-1)*25+tid)*2+0]; q1 = w1[((i-1)*25+tid)*2+1]; qb = b1[(i-1)*25+tid];
      }
      w1s[tid][0]=q0; w1s[tid][1]=q1; b1s[tid]=qb;
    }
    short8 Afc[2][3];
    #pragma unroll
    for (int mt = 0; mt < 2; ++mt)
      #pragma unroll
      for (int tp = 0; tp < 3; ++tp)
        Afc[mt][tp] = *reinterpret_cast<const short8*>(convA + (((i*2+mt)*3+tp)*64 + lane)*8);
    __syncthreads();

    for (int grp = wv; grp < 17; grp += 4){
      const int myc = grp*16 + (lane & 15);        // halo'd column index
      const int kof = (lane >> 4) * 8;
      const u16* zp = zin + myc*ZSTR + kof;        // tap0 reads col-1 (guard offset +1)
      short8 bt0 = *reinterpret_cast<const short8*>(zp);
      short8 bt1 = *reinterpret_cast<const short8*>(zp + ZSTR);
      short8 bt2 = *reinterpret_cast<const short8*>(zp + 2*ZSTR);
      f32x4 a0 = {0.f,0.f,0.f,0.f}, a1 = {0.f,0.f,0.f,0.f};
      a0 = __builtin_amdgcn_mfma_f32_16x16x32_bf16(Afc[0][0], bt0, a0, 0,0,0);
      a0 = __builtin_amdgcn_mfma_f32_16x16x32_bf16(Afc[0][1], bt1, a0, 0,0,0);
      a0 = __builtin_amdgcn_mfma_f32_16x16x32_bf16(Afc[0][2], bt2, a0, 0,0,0);
      a1 = __builtin_amdgcn_mfma_f32_16x16x32_bf16(Afc[1][0], bt0, a1, 0,0,0);
      a1 = __builtin_amdgcn_mfma_f32_16x16x32_bf16(Afc[1][1], bt1, a1, 0,0,0);
      a1 = __builtin_amdgcn_mfma_f32_16x16x32_bf16(Afc[1][2], bt2, a1, 0,0,0);
      const int t = t0 - HALO + myc;
      const bool tok = (unsigned)t < (unsigned)T_LEN;
      const bool interior = (myc >= HALO) && (myc < HALO + TILE);
      float xl0 = 0.f, xl1 = 0.f;
      if (i > 0){ xl0 = lfs[2*i-2][myc]; xl1 = lfs[2*i-1][myc]; }
      #pragma unroll
      for (int mt = 0; mt < 2; ++mt){
        #pragma unroll
        for (int r = 0; r < 4; ++r){
          const int w = mt*16 + (lane>>4)*4 + r;   // C/D row (m89-verified)
          float av = mt ? a1[r] : a0[r];
          float y  = fmaxf(av*abn[w] + cbn[w], 0.f);
          y = tok ? y : 0.f;
          if constexpr (PASS == 1){
            if (interior) ysum[mt*4+r] += y;
          }
          if constexpr (PASS == 2){
            if (interior && w < 25) glT[(myc-HALO)*GSTR + 25*i + w] = f2bf(y * g5[i]);
          }
          if (i > 0){
            float zv = 0.f;
            if (w < 25 && tok) zv = y + b1s[w] + w1s[w][0]*xl0 + w1s[w][1]*xl1;
            zout[(myc+1)*ZSTR + w] = f2bf(zv);
          }
        }
      }
    }
    if constexpr (PASS == 1){                // per-layer flush of channel sums
      #pragma unroll
      for (int mt = 0; mt < 2; ++mt){
        #pragma unroll
        for (int r = 0; r < 4; ++r){
          float v = ysum[mt*4+r];
          v += __shfl_xor(v, 1); v += __shfl_xor(v, 2);
          v += __shfl_xor(v, 4); v += __shfl_xor(v, 8);
          if ((lane & 15) == 0){
            const int w = mt*16 + (lane>>4)*4 + r;
            if (w < 25) atomicAdd(&accC[25*i + w], v);
          }
          ysum[mt*4+r] = 0.f;
        }
      }
    }
    __syncthreads();
    u16* tz = zin; zin = zout; zout = tz;
  }

  if constexpr (PASS == 1){
    if (tid < 128) outpart[(b*NTILE + tblk)*128 + tid] = accC[tid];
    return;
  }

  if constexpr (PASS == 2){
    // ---- GEMM: [128 x 160] @ [160 x 256] ; wave = 4 m-tiles x 8 n-tiles ----
    const int mt0 = (wv & 1) * 4;
    const int nt0 = (wv >> 1) * 8;
    const f32x4 vzero = {0.f,0.f,0.f,0.f};
    f32x4 acc[8][4];
    #pragma unroll
    for (int n2 = 0; n2 < 8; ++n2)
      #pragma unroll
      for (int m2 = 0; m2 < 4; ++m2) acc[n2][m2] = vzero;
    #pragma unroll
    for (int kt = 0; kt < 5; ++kt){
      short8 Am[4];
      #pragma unroll
      for (int m2 = 0; m2 < 4; ++m2)
        Am[m2] = *reinterpret_cast<const short8*>(projA + (((mt0+m2)*5 + kt)*64 + lane)*8);
      #pragma unroll
      for (int n2 = 0; n2 < 8; ++n2){
        const short8 Bm = *reinterpret_cast<const short8*>(
            &glT[((nt0+n2)*16 + (lane & 15))*GSTR + kt*32 + (lane >> 4)*8]);
        #pragma unroll
        for (int m2 = 0; m2 < 4; ++m2)
          acc[n2][m2] = __builtin_amdgcn_mfma_f32_16x16x32_bf16(Am[m2], Bm, acc[n2][m2], 0,0,0);
      }
    }
    // epilogue: final BN + ReLU + column-sum
    float psum[4][4];
    #pragma unroll
    for (int m2 = 0; m2 < 4; ++m2)
      #pragma unroll
      for (int r = 0; r < 4; ++r) psum[m2][r] = 0.f;
    #pragma unroll
    for (int n2 = 0; n2 < 8; ++n2)
      #pragma unroll
      for (int m2 = 0; m2 < 4; ++m2)
        #pragma unroll
        for (int r = 0; r < 4; ++r){
          const int c = (mt0+m2)*16 + (lane>>4)*4 + r;
          psum[m2][r] += fmaxf(acc[n2][m2][r]*Af[c] + Bf[c], 0.f);
        }
    #pragma unroll
    for (int m2 = 0; m2 < 4; ++m2)
      #pragma unroll
      for (int r = 0; r < 4; ++r){
        float v = psum[m2][r];
        v += __shfl_xor(v, 1); v += __shfl_xor(v, 2);
        v += __shfl_xor(v, 4); v += __shfl_xor(v, 8);
        if ((lane & 15) == 0){
          const int c = (mt0+m2)*16 + (lane>>4)*4 + r;
          atomicAdd(&accC[c], v);
        }
      }
    __syncthreads();
    if (tid < 128) outpart[(b*NTILE + tblk)*128 + tid] = accC[tid];
  }
}

// ---------------------------------------------------------------------------
// K2: gating MLP  (avg -> 31 -> 5 -> sigmoid)
// ---------------------------------------------------------------------------
__global__ void gate_kernel(const float* __restrict__ avgpart,
                            const float* __restrict__ gw1, const float* __restrict__ gb1,
                            const float* __restrict__ gw2, const float* __restrict__ gb2,
                            float* __restrict__ gatews)
{
  int b = blockIdx.x, tid = threadIdx.x;
  __shared__ float avg[128], h1[31];
  for (int c = tid; c < 128; c += 64){
    float s = 0.f;
    for (int tb = 0; tb < NTILE; ++tb) s += avgpart[(b*NTILE + tb)*128 + c];
    avg[c] = s * (1.f / 4096.f);
  }
  __syncthreads();
  if (tid < 31){
    float s = gb1[tid];
    for (int c = 0; c < 125; ++c) s += avg[c] * gw1[tid*125 + c];
    h1[tid] = fmaxf(s, 0.f);
  }
  __syncthreads();
  if (tid < 5){
    float s = gb2[tid];
    for (int j = 0; j < 31; ++j) s += h1[j] * gw2[tid*31 + j];
    gatews[b*5 + tid] = 1.f / (1.f + expf(-s));
  }
}

// ---------------------------------------------------------------------------
// K4: pooled mean -> LayerNorm -> fc1 + LeakyReLU(0.2) -> fc2
// ---------------------------------------------------------------------------
__global__ void final_kernel(const float* __restrict__ pooledpart,
                             const float* __restrict__ ln_g, const float* __restrict__ ln_b,
                             const float* __restrict__ fc1_w, const float* __restrict__ fc1_b,
                             const float* __restrict__ fc2_w, const float* __restrict__ fc2_b,
                             float* __restrict__ out)
{
  int b = blockIdx.x, tid = threadIdx.x;
  __shared__ float pl[125], nr[125], hh[64], st[2];
  for (int c = tid; c < 125; c += 64){
    float s = 0.f;
    for (int tb = 0; tb < NTILE; ++tb) s += pooledpart[(b*NTILE + tb)*128 + c];
    pl[c] = s * (1.f / 4096.f);
  }
  __syncthreads();
  if (tid == 0){
    float mu = 0.f;
    for (int c = 0; c < 125; ++c) mu += pl[c];
    mu /= 125.f;
    float va = 0.f;
    for (int c = 0; c < 125; ++c){ float d = pl[c] - mu; va += d*d; }
    va /= 125.f;
    st[0] = mu; st[1] = rsqrtf(va + 1e-5f);
  }
  __syncthreads();
  for (int c = tid; c < 125; c += 64)
    nr[c] = (pl[c] - st[0]) * st[1] * ln_g[c] + ln_b[c];
  __syncthreads();
  {
    float s = fc1_b[tid];
    for (int c = 0; c < 125; ++c) s += nr[c] * fc1_w[tid*125 + c];
    hh[tid] = (s > 0.f) ? s : 0.2f * s;
  }
  __syncthreads();
  if (tid < 2){
    float s = fc2_b[tid];
    for (int j = 0; j < 64; ++j) s += hh[j] * fc2_w[tid*64 + j];
    out[b*2 + tid] = s;
  }
}

// ---------------------------------------------------------------------------
extern "C" void kernel_launch(void* const* d_in, const int* in_sizes, int n_in,
                              void* d_out, int out_size, void* d_ws, size_t ws_size,
                              hipStream_t stream)
{
  const float* lf    = (const float*)d_in[0];
  const float* w1    = (const float*)d_in[1];
  const float* b1    = (const float*)d_in[2];
  const float* w3    = (const float*)d_in[3];
  const float* b3    = (const float*)d_in[4];
  const float* bn_g  = (const float*)d_in[5];
  const float* bn_b  = (const float*)d_in[6];
  const float* bn_m  = (const float*)d_in[7];
  const float* bn_v  = (const float*)d_in[8];
  const float* gw1   = (const float*)d_in[9];
  const float* gb1   = (const float*)d_in[10];
  const float* gw2   = (const float*)d_in[11];
  const float* gb2   = (const float*)d_in[12];
  const float* id_w  = (const float*)d_in[13];
  const float* id_b  = (const float*)d_in[14];
  const float* pf_w  = (const float*)d_in[15];
  const float* pf_b  = (const float*)d_in[16];
  const float* fbn_g = (const float*)d_in[17];
  const float* fbn_b = (const float*)d_in[18];
  const float* fbn_m = (const float*)d_in[19];
  const float* fbn_v = (const float*)d_in[20];
  const float* ln_g  = (const float*)d_in[21];
  const float* ln_b  = (const float*)d_in[22];
  const float* fc1_w = (const float*)d_in[23];
  const float* fc1_b = (const float*)d_in[24];
  const float* fc2_w = (const float*)d_in[25];
  const float* fc2_b = (const float*)d_in[26];

  char* ws = (char*)d_ws;
  float* avgpart    = (float*)(ws);                         // 1 MB
  float* pooledpart = (float*)(ws + (1u<<20));              // 1 MB
  float* gatews     = (float*)(ws + (2u<<20));              // 4 KB reserved
  u16*   projA      = (u16*)  (ws + (2u<<20) + 4096);       // 40960 B
  u16*   convA      = (u16*)  (ws + (2u<<20) + 4096 + 40960); // 24576 B

  prep_kernel<<<128, 256, 0, stream>>>(w3, pf_w, id_w, projA, convA);
  dim3 grid(NTILE, 128);
  pass_kernel<1><<<grid, 256, 0, stream>>>(lf, w1, b1, b3, bn_g, bn_b, bn_m, bn_v,
      convA, projA, gatews, pf_b, id_b, fbn_g, fbn_b, fbn_m, fbn_v, avgpart);
  gate_kernel<<<128, 64, 0, stream>>>(avgpart, gw1, gb1, gw2, gb2, gatews);
  pass_kernel<2><<<grid, 256, 0, stream>>>(lf, w1, b1, b3, bn_g, bn_b, bn_m, bn_v,
      convA, projA, gatews, pf_b, id_b, fbn_g, fbn_b, fbn_m, fbn_v, pooledpart);
  final_kernel<<<128, 64, 0, stream>>>(pooledpart, ln_g, ln_b, fc1_w, fc1_b,
      fc2_w, fc2_b, (float*)d_out);
}

// Round 2
// 434.865 us; speedup vs baseline: 1.2439x; 1.2439x over previous
//
#include <hip/hip_runtime.h>
#include <stdint.h>

typedef unsigned short u16;
typedef unsigned int   u32;
using short8 = __attribute__((ext_vector_type(8))) short;   // 8 bf16
using f32x4  = __attribute__((ext_vector_type(4))) float;

__device__ __forceinline__ u16 f2bf(float f){
  u32 u = __builtin_bit_cast(u32, f);
  u = u + 0x7fffu + ((u >> 16) & 1u);     // RNE
  return (u16)(u >> 16);
}
__device__ __forceinline__ u32 packbf2(float a, float b){
  // low16 = bf16(a), high16 = bf16(b); round-half-up (1 add per value)
  u32 ua = __builtin_bit_cast(u32, a) + 0x8000u;
  u32 ub = __builtin_bit_cast(u32, b) + 0x8000u;
  return (ua >> 16) | (ub & 0xffff0000u);
}

// ---------------------------------------------------------------------------
// K0: conv3 weight MFMA A-fragments (4 layers x 2 mtiles x 3 taps, 32x32)
// k-map: k = 8*(lane>>4)+j  (consistent A/B mapping; any HW k-permute cancels)
// ---------------------------------------------------------------------------
__global__ void prep_kernel(const float* __restrict__ w3, u16* __restrict__ convA){
  int idx = blockIdx.x*256 + threadIdx.x;
  if (idx >= 4*2*3*64*8) return;
  int j = idx & 7, l = (idx>>3) & 63, frag = idx >> 9;
  int tap = frag % 3, mt = (frag/3) & 1, lay = frag/6;
  int m = mt*16 + (l & 15), k = (l>>4)*8 + j;
  float v = 0.f;
  if (m < 25 && k < 25) v = w3[((lay*25 + m)*25 + k)*3 + tap];
  convA[idx] = f2bf(v);
}

// ---------------------------------------------------------------------------
// pass_kernel<PASS,CT>: per-wave independent stripe of (CT-2)*16 interior cols,
// halo 16 each side (>= 4 conv layers). No barriers in the main loop.
// PASS1: conv chain -> per-channel column sums (gate numerator partials).
// PASS2: conv chain + fused gated proj GEMM (gate folded in Ab) + identity
//        + final BN/ReLU + pooled column-sum partials.
// ---------------------------------------------------------------------------
template<int PASS, int CT>
__global__ __launch_bounds__(256)
void pass_kernel(const float* __restrict__ lfg,
                 const float* __restrict__ w1g, const float* __restrict__ b1g,
                 const float* __restrict__ b3g,
                 const float* __restrict__ bng, const float* __restrict__ bnb,
                 const float* __restrict__ bnm, const float* __restrict__ bnv,
                 const u16* __restrict__ convA, const u16* __restrict__ Ab,
                 const float* __restrict__ pfb, const float* __restrict__ idb,
                 const float* __restrict__ fbg, const float* __restrict__ fbb,
                 const float* __restrict__ fbm, const float* __restrict__ fbv,
                 float* __restrict__ outpart)
{
  constexpr int IS   = (CT-2)*16;       // interior cols per wave
  constexpr int LFC  = 4*IS + 32;       // lf cols per block
  constexpr int CZ   = 16*CT + 2;       // z cols incl guards
  constexpr int NBLK = 4096/(4*IS);     // blocks per batch row

  __shared__ __align__(16) u16 zws[4][CZ*40];                       // ch stride 40
  __shared__ __align__(16) u16 yTs[(PASS==2)?4:1][(PASS==2)?(32*40):8];
  __shared__ float lfs[10][LFC];
  __shared__ float abnA[5][32], cbnA[5][32], w1A[5][32][2], b1A[5][32];
  __shared__ float accC[(PASS==1)?160:4];
  __shared__ float pooled[(PASS==2)?128:4];
  __shared__ float AfS[(PASS==2)?128:4], BfS[(PASS==2)?128:4];

  const int tid  = threadIdx.x;
  const int lane = tid & 63, wv = tid >> 6;
  const int q = lane >> 4, c16 = lane & 15;
  const int b = blockIdx.y, blk = blockIdx.x;
  const int stripe = blk*4 + wv;
  const int tbase  = stripe*IS - 16;    // t of local col 0
  const int colB   = blk*(4*IS) - 16;   // t of lfs[][0]

  for (int x = tid; x < 4*CZ*20; x += 256) ((u32*)zws)[x] = 0u;
  if constexpr (PASS==2){
    for (int x = tid; x < 4*32*20; x += 256) ((u32*)yTs)[x] = 0u;
  }
  for (int x = tid; x < 10*LFC; x += 256){
    int ch = x / LFC, u = x - ch*LFC;
    int t = colB + u;
    lfs[ch][u] = ((unsigned)t < 4096u) ? lfg[(b*10 + ch)*4096 + t] : 0.f;
  }
  if (tid < 160){
    int i = tid >> 5, ch = tid & 31;
    float a=0.f, c=0.f, w0=0.f, w1v=0.f, bb=0.f;
    if (ch < 25){
      float g = bng[i*25+ch], be = bnb[i*25+ch], m = bnm[i*25+ch], v = bnv[i*25+ch];
      a = g * rsqrtf(v + 1e-5f);
      c = (i==4) ? (be - m*a) : ((b3g[i*25+ch] - m)*a + be);  // fold b3 into shift
      w0 = w1g[(i*25+ch)*2+0]; w1v = w1g[(i*25+ch)*2+1]; bb = b1g[i*25+ch];
    }
    abnA[i][ch]=a; cbnA[i][ch]=c; w1A[i][ch][0]=w0; w1A[i][ch][1]=w1v; b1A[i][ch]=bb;
  }
  if constexpr (PASS==1){ if (tid < 160) accC[tid] = 0.f; }
  if constexpr (PASS==2){
    if (tid < 128){
      pooled[tid] = 0.f;
      float fs=0.f, fsh=0.f;
      if (tid < 125){
        fs  = fbg[tid]*rsqrtf(fbv[tid]+1e-5f);
        fsh = (pfb[tid]+idb[tid]-fbm[tid])*fs + fbb[tid];
      }
      AfS[tid]=fs; BfS[tid]=fsh;
    }
  }
  __syncthreads();                       // the only block-wide barrier before end

  u16* z  = zws[wv];
  u16* yt = yTs[(PASS==2)?wv:0];
  const int lfo = wv*IS;

  f32x4 pacc[2][8];
  if constexpr (PASS==2){
    #pragma unroll
    for (int n2 = 0; n2 < 2; ++n2)
      #pragma unroll
      for (int m2 = 0; m2 < 8; ++m2) pacc[n2][m2] = (f32x4){0.f,0.f,0.f,0.f};
  }

  // ---------------- prologue: y4 (1x1 conv + BN + relu), z3 = xs3 + y4 ----
  {
    float s4[8];
    #pragma unroll
    for (int m2 = 0; m2 < 8; ++m2) s4[m2] = 0.f;
    #pragma unroll
    for (int ct = 0; ct < CT; ++ct){
      const int lc = 16*ct + c16;
      const int t  = tbase + lc;
      const bool tok   = (unsigned)t < 4096u;
      const bool inter = (ct >= 1) && (ct <= CT-2);
      const float lf6 = lfs[6][lfo+lc], lf7 = lfs[7][lfo+lc];
      const float lf8 = lfs[8][lfo+lc], lf9 = lfs[9][lfo+lc];
      #pragma unroll
      for (int mt = 0; mt < 2; ++mt){
        float zv[4], yv[4];
        #pragma unroll
        for (int r = 0; r < 4; ++r){
          const int ch = mt*16 + 4*q + r;
          float xs4 = b1A[4][ch] + w1A[4][ch][0]*lf8 + w1A[4][ch][1]*lf9;
          float y4  = fmaxf(abnA[4][ch]*xs4 + cbnA[4][ch], 0.f);
          float xs3 = b1A[3][ch] + w1A[3][ch][0]*lf6 + w1A[3][ch][1]*lf7;
          zv[r] = tok ? (xs3 + y4) : 0.f;
          yv[r] = y4;
          if (PASS==1 && inter) s4[mt*4+r] += y4;
        }
        uint2 wz; wz.x = packbf2(zv[0], zv[1]); wz.y = packbf2(zv[2], zv[3]);
        *(uint2*)&z[(lc+1)*40 + mt*16 + 4*q] = wz;
        if (PASS==2 && inter){
          uint2 wy; wy.x = packbf2(yv[0], yv[1]); wy.y = packbf2(yv[2], yv[3]);
          *(uint2*)&yt[(lc-16)*40 + mt*16 + 4*q] = wy;
        }
      }
    }
    if constexpr (PASS==1){
      #pragma unroll
      for (int m2 = 0; m2 < 8; ++m2){
        float v = s4[m2];
        v += __shfl_xor(v,1); v += __shfl_xor(v,2); v += __shfl_xor(v,4); v += __shfl_xor(v,8);
        if (c16 == 0){
          int ch = (m2>>2)*16 + 4*q + (m2&3);
          if (ch < 25) atomicAdd(&accC[4*32+ch], v);
        }
      }
    }
  }

  if constexpr (PASS==2){
    { // proj kt = 4 (scale 4)
      short8 Am[8];
      #pragma unroll
      for (int m2 = 0; m2 < 8; ++m2)
        Am[m2] = *(const short8*)(Ab + b*24576 + ((4*8+m2)*64 + lane)*8);
      #pragma unroll
      for (int n2 = 0; n2 < 2; ++n2){
        const short8 Bm = *(const short8*)&yt[(n2*16 + c16)*40 + 8*q];
        #pragma unroll
        for (int m2 = 0; m2 < 8; ++m2)
          pacc[n2][m2] = __builtin_amdgcn_mfma_f32_16x16x32_bf16(Am[m2], Bm, pacc[n2][m2], 0,0,0);
      }
    }
    { // proj kt = 5 (identity, lf channels 0..9)
      short8 Am[8];
      #pragma unroll
      for (int m2 = 0; m2 < 8; ++m2)
        Am[m2] = *(const short8*)(Ab + b*24576 + ((5*8+m2)*64 + lane)*8);
      #pragma unroll
      for (int n2 = 0; n2 < 2; ++n2){
        short8 Bm;
        #pragma unroll
        for (int j = 0; j < 8; ++j){
          int k = 8*q + j;
          float v = (k < 10) ? lfs[k][lfo + 16 + n2*16 + c16] : 0.f;
          Bm[j] = (short)f2bf(v);
        }
        #pragma unroll
        for (int m2 = 0; m2 < 8; ++m2)
          pacc[n2][m2] = __builtin_amdgcn_mfma_f32_16x16x32_bf16(Am[m2], Bm, pacc[n2][m2], 0,0,0);
      }
    }
  }

  // ---------------- conv layers i = 3..0 (wave-private, no barriers) ------
  for (int i = 3; i >= 0; --i){
    short8 Ac0[3], Ac1[3];
    #pragma unroll
    for (int tp = 0; tp < 3; ++tp){
      Ac0[tp] = *(const short8*)(convA + (((i*2+0)*3+tp)*64 + lane)*8);
      Ac1[tp] = *(const short8*)(convA + (((i*2+1)*3+tp)*64 + lane)*8);
    }
    float ysum[8];
    #pragma unroll
    for (int m2 = 0; m2 < 8; ++m2) ysum[m2] = 0.f;

    short8 fA[3], fB[3];
    {
      const u16* p = z + c16*40 + 8*q;
      fA[0] = *(const short8*)(p);
      fA[1] = *(const short8*)(p + 40);
      fA[2] = *(const short8*)(p + 80);
    }
    #pragma unroll
    for (int ct = 0; ct < CT; ++ct){
      short8* cur = (ct & 1) ? fB : fA;
      short8* nxt = (ct & 1) ? fA : fB;
      if (ct < CT-1){                    // prefetch next tile's taps (before
        const u16* p = z + (16*(ct+1) + c16)*40 + 8*q;   // this tile's writes!)
        nxt[0] = *(const short8*)(p);
        nxt[1] = *(const short8*)(p + 40);
        nxt[2] = *(const short8*)(p + 80);
      }
      __builtin_amdgcn_sched_barrier(0); // pin: reads above, writes below
      f32x4 a0 = {0.f,0.f,0.f,0.f}, a1 = {0.f,0.f,0.f,0.f};
      #pragma unroll
      for (int tp = 0; tp < 3; ++tp){
        a0 = __builtin_amdgcn_mfma_f32_16x16x32_bf16(Ac0[tp], cur[tp], a0, 0,0,0);
        a1 = __builtin_amdgcn_mfma_f32_16x16x32_bf16(Ac1[tp], cur[tp], a1, 0,0,0);
      }
      const int lc = 16*ct + c16;
      const int t  = tbase + lc;
      const bool tok   = (unsigned)t < 4096u;
      const bool inter = (ct >= 1) && (ct <= CT-2);
      float lfa = 0.f, lfb = 0.f;
      if (i > 0){ lfa = lfs[2*i-2][lfo+lc]; lfb = lfs[2*i-1][lfo+lc]; }
      #pragma unroll
      for (int mt = 0; mt < 2; ++mt){
        float yv[4], zv[4];
        #pragma unroll
        for (int r = 0; r < 4; ++r){
          const int ch = mt*16 + 4*q + r;              // C/D row (m89)
          const float av = mt ? a1[r] : a0[r];
          float y = fmaxf(av*abnA[i][ch] + cbnA[i][ch], 0.f);
          yv[r] = y;
          if (PASS==1 && inter) ysum[mt*4+r] += y;
          if (i > 0) zv[r] = tok ? (y + b1A[i-1][ch] + w1A[i-1][ch][0]*lfa
                                      + w1A[i-1][ch][1]*lfb) : 0.f;
        }
        if (PASS==2 && inter){
          uint2 wy; wy.x = packbf2(yv[0], yv[1]); wy.y = packbf2(yv[2], yv[3]);
          *(uint2*)&yt[(lc-16)*40 + mt*16 + 4*q] = wy;
        }
        if (i > 0){
          uint2 wz; wz.x = packbf2(zv[0], zv[1]); wz.y = packbf2(zv[2], zv[3]);
          *(uint2*)&z[(lc+1)*40 + mt*16 + 4*q] = wz;
        }
      }
    }
    if constexpr (PASS==1){
      #pragma unroll
      for (int m2 = 0; m2 < 8; ++m2){
        float v = ysum[m2];
        v += __shfl_xor(v,1); v += __shfl_xor(v,2); v += __shfl_xor(v,4); v += __shfl_xor(v,8);
        if (c16 == 0){
          int ch = (m2>>2)*16 + 4*q + (m2&3);
          if (ch < 25) atomicAdd(&accC[i*32+ch], v);
        }
      }
    }
    if constexpr (PASS==2){                            // proj kt = i
      short8 Am[8];
      #pragma unroll
      for (int m2 = 0; m2 < 8; ++m2)
        Am[m2] = *(const short8*)(Ab + b*24576 + ((i*8+m2)*64 + lane)*8);
      #pragma unroll
      for (int n2 = 0; n2 < 2; ++n2){
        const short8 Bm = *(const short8*)&yt[(n2*16 + c16)*40 + 8*q];
        #pragma unroll
        for (int m2 = 0; m2 < 8; ++m2)
          pacc[n2][m2] = __builtin_amdgcn_mfma_f32_16x16x32_bf16(Am[m2], Bm, pacc[n2][m2], 0,0,0);
      }
    }
  }

  if constexpr (PASS==1){
    __syncthreads();
    if (tid < 160) outpart[(b*NBLK + blk)*160 + tid] = accC[tid];
  }
  if constexpr (PASS==2){
    #pragma unroll
    for (int m2 = 0; m2 < 8; ++m2){
      float p0=0.f,p1=0.f,p2=0.f,p3=0.f;
      const int chb = m2*16 + 4*q;
      #pragma unroll
      for (int n2 = 0; n2 < 2; ++n2){
        p0 += fmaxf(pacc[n2][m2][0]*AfS[chb+0] + BfS[chb+0], 0.f);
        p1 += fmaxf(pacc[n2][m2][1]*AfS[chb+1] + BfS[chb+1], 0.f);
        p2 += fmaxf(pacc[n2][m2][2]*AfS[chb+2] + BfS[chb+2], 0.f);
        p3 += fmaxf(pacc[n2][m2][3]*AfS[chb+3] + BfS[chb+3], 0.f);
      }
      p0 += __shfl_xor(p0,1); p0 += __shfl_xor(p0,2); p0 += __shfl_xor(p0,4); p0 += __shfl_xor(p0,8);
      p1 += __shfl_xor(p1,1); p1 += __shfl_xor(p1,2); p1 += __shfl_xor(p1,4); p1 += __shfl_xor(p1,8);
      p2 += __shfl_xor(p2,1); p2 += __shfl_xor(p2,2); p2 += __shfl_xor(p2,4); p2 += __shfl_xor(p2,8);
      p3 += __shfl_xor(p3,1); p3 += __shfl_xor(p3,2); p3 += __shfl_xor(p3,4); p3 += __shfl_xor(p3,8);
      if (c16 == 0){
        atomicAdd(&pooled[chb+0], p0); atomicAdd(&pooled[chb+1], p1);
        atomicAdd(&pooled[chb+2], p2); atomicAdd(&pooled[chb+3], p3);
      }
    }
    __syncthreads();
    if (tid < 128) outpart[(b*NBLK + blk)*128 + tid] = pooled[tid];
  }
}

// ---------------------------------------------------------------------------
// K2: gating MLP + build per-batch gated proj A-fragments (K = 6*32:
//     kt 0..4 = scales (gated), kt 5 = identity (gate 1))
// ---------------------------------------------------------------------------
__global__ void gate_kernel(const float* __restrict__ partialC,
                            const float* __restrict__ gw1, const float* __restrict__ gb1,
                            const float* __restrict__ gw2, const float* __restrict__ gb2,
                            const float* __restrict__ pf_w, const float* __restrict__ id_w,
                            u16* __restrict__ Ab)
{
  int b = blockIdx.x, tid = threadIdx.x;
  __shared__ float avg[125], h1[31], g[6];
  if (tid < 160){
    float s = 0.f;
    for (int k = 0; k < 16; ++k) s += partialC[(b*16+k)*160 + tid];
    int sc = tid >> 5, ch = tid & 31;
    if (ch < 25) avg[sc*25+ch] = s * (1.f/4096.f);
  }
  __syncthreads();
  if (tid < 31){
    float s = gb1[tid];
    for (int c = 0; c < 125; ++c) s += avg[c] * gw1[tid*125 + c];
    h1[tid] = fmaxf(s, 0.f);
  }
  __syncthreads();
  if (tid < 5){
    float s = gb2[tid];
    for (int j = 0; j < 31; ++j) s += h1[j] * gw2[tid*31 + j];
    g[tid] = 1.f / (1.f + expf(-s));
  }
  if (tid == 5) g[5] = 1.f;
  __syncthreads();
  for (int idx = tid; idx < 24576; idx += 256){
    int j = idx & 7, l = (idx>>3) & 63, mt = (idx>>9) & 7, kt = idx >> 12;
    int m = mt*16 + (l & 15), k = (l>>4)*8 + j;
    float v = 0.f;
    if (m < 125){
      if (kt < 5){ if (k < 25) v = pf_w[m*125 + kt*25 + k] * g[kt]; }
      else       { if (k < 10) v = id_w[m*10 + k]; }
    }
    Ab[b*24576 + idx] = f2bf(v);
  }
}

// ---------------------------------------------------------------------------
// K4: pooled mean -> LayerNorm -> fc1 + LeakyReLU(0.2) -> fc2
// ---------------------------------------------------------------------------
__global__ void final_kernel(const float* __restrict__ pooledpart,
                             const float* __restrict__ ln_g, const float* __restrict__ ln_b,
                             const float* __restrict__ fc1_w, const float* __restrict__ fc1_b,
                             const float* __restrict__ fc2_w, const float* __restrict__ fc2_b,
                             float* __restrict__ out)
{
  int b = blockIdx.x, tid = threadIdx.x;
  __shared__ float pl[125], nr[125], hh[64], st[2];
  for (int c = tid; c < 125; c += 64){
    float s = 0.f;
    for (int k = 0; k < 32; ++k) s += pooledpart[(b*32+k)*128 + c];
    pl[c] = s * (1.f/4096.f);
  }
  __syncthreads();
  if (tid == 0){
    float mu = 0.f;
    for (int c = 0; c < 125; ++c) mu += pl[c];
    mu /= 125.f;
    float va = 0.f;
    for (int c = 0; c < 125; ++c){ float d = pl[c] - mu; va += d*d; }
    va /= 125.f;
    st[0] = mu; st[1] = rsqrtf(va + 1e-5f);
  }
  __syncthreads();
  for (int c = tid; c < 125; c += 64)
    nr[c] = (pl[c] - st[0]) * st[1] * ln_g[c] + ln_b[c];
  __syncthreads();
  {
    float s = fc1_b[tid];
    for (int c = 0; c < 125; ++c) s += nr[c] * fc1_w[tid*125 + c];
    hh[tid] = (s > 0.f) ? s : 0.2f * s;
  }
  __syncthreads();
  if (tid < 2){
    float s = fc2_b[tid];
    for (int j = 0; j < 64; ++j) s += hh[j] * fc2_w[tid*64 + j];
    out[b*2 + tid] = s;
  }
}

// ---------------------------------------------------------------------------
extern "C" void kernel_launch(void* const* d_in, const int* in_sizes, int n_in,
                              void* d_out, int out_size, void* d_ws, size_t ws_size,
                              hipStream_t stream)
{
  const float* lf    = (const float*)d_in[0];
  const float* w1    = (const float*)d_in[1];
  const float* b1    = (const float*)d_in[2];
  const float* w3    = (const float*)d_in[3];
  const float* b3    = (const float*)d_in[4];
  const float* bn_g  = (const float*)d_in[5];
  const float* bn_b  = (const float*)d_in[6];
  const float* bn_m  = (const float*)d_in[7];
  const float* bn_v  = (const float*)d_in[8];
  const float* gw1   = (const float*)d_in[9];
  const float* gb1   = (const float*)d_in[10];
  const float* gw2   = (const float*)d_in[11];
  const float* gb2   = (const float*)d_in[12];
  const float* id_w  = (const float*)d_in[13];
  const float* id_b  = (const float*)d_in[14];
  const float* pf_w  = (const float*)d_in[15];
  const float* pf_b  = (const float*)d_in[16];
  const float* fbn_g = (const float*)d_in[17];
  const float* fbn_b = (const float*)d_in[18];
  const float* fbn_m = (const float*)d_in[19];
  const float* fbn_v = (const float*)d_in[20];
  const float* ln_g  = (const float*)d_in[21];
  const float* ln_b  = (const float*)d_in[22];
  const float* fc1_w = (const float*)d_in[23];
  const float* fc1_b = (const float*)d_in[24];
  const float* fc2_w = (const float*)d_in[25];
  const float* fc2_b = (const float*)d_in[26];

  char* ws = (char*)d_ws;
  float* partialC   = (float*)ws;                                  // 1,310,720 B
  float* pooledpart = (float*)(ws + 1310720);                      // 2,097,152 B
  u16*   Ab         = (u16*)(ws + 1310720 + 2097152);              // 6,291,456 B
  u16*   convA      = (u16*)(ws + 1310720 + 2097152 + 6291456);    //    24,576 B

  prep_kernel<<<48, 256, 0, stream>>>(w3, convA);
  dim3 g1(16, 128), g2(32, 128);
  pass_kernel<1,6><<<g1, 256, 0, stream>>>(lf, w1, b1, b3, bn_g, bn_b, bn_m, bn_v,
      convA, Ab, pf_b, id_b, fbn_g, fbn_b, fbn_m, fbn_v, partialC);
  gate_kernel<<<128, 256, 0, stream>>>(partialC, gw1, gb1, gw2, gb2, pf_w, id_w, Ab);
  pass_kernel<2,4><<<g2, 256, 0, stream>>>(lf, w1, b1, b3, bn_g, bn_b, bn_m, bn_v,
      convA, Ab, pf_b, id_b, fbn_g, fbn_b, fbn_m, fbn_v, pooledpart);
  final_kernel<<<128, 64, 0, stream>>>(pooledpart, ln_g, ln_b, fc1_w, fc1_b,
      fc2_w, fc2_b, (float*)d_out);
}

// Round 3
// 357.399 us; speedup vs baseline: 1.5135x; 1.2167x over previous
//
#include <hip/hip_runtime.h>
#include <stdint.h>

typedef unsigned short u16;
typedef unsigned int   u32;
using short8 = __attribute__((ext_vector_type(8))) short;   // 8 bf16
using f32x4  = __attribute__((ext_vector_type(4))) float;

__device__ __forceinline__ u16 f2bf(float f){
  u32 u = __builtin_bit_cast(u32, f);
  u = u + 0x7fffu + ((u >> 16) & 1u);     // RNE
  return (u16)(u >> 16);
}
__device__ __forceinline__ u32 packbf2(float a, float b){
  u32 ua = __builtin_bit_cast(u32, a) + 0x8000u;
  u32 ub = __builtin_bit_cast(u32, b) + 0x8000u;
  return (ua >> 16) | (ub & 0xffff0000u);
}

// ---------------------------------------------------------------------------
// K0: folded conv3 A-fragments. Per layer/mtile/tap, 32x32, k-map k=8*(l>>4)+j.
// Rows (m) pre-scaled by BN scale a_i. K-cols: 0-24 = y channels (a*W3),
// 25 = bias row (a * sum_c W3*b1, pairs with valid-indicator B-row),
// 26,27 = lf rows (a * sum_c W3*W1[:,e]).  28-31 zero.
// ---------------------------------------------------------------------------
__global__ void prep_kernel(const float* __restrict__ w3,
                            const float* __restrict__ w1,
                            const float* __restrict__ b1,
                            const float* __restrict__ bng,
                            const float* __restrict__ bnv,
                            u16* __restrict__ convA)
{
  int idx = blockIdx.x*256 + threadIdx.x;
  if (idx >= 4*2*3*64*8) return;
  int j = idx & 7, l = (idx>>3) & 63, frag = idx >> 9;
  int tap = frag % 3, mt = (frag/3) & 1, lay = frag/6;
  int m = mt*16 + (l & 15);
  int k = (l>>4)*8 + j;
  float v = 0.f;
  if (m < 25){
    float a = bng[lay*25+m] * rsqrtf(bnv[lay*25+m] + 1e-5f);
    if (k < 25){
      v = a * w3[((lay*25+m)*25 + k)*3 + tap];
    } else if (k == 25){                       // bias row (x valid-indicator)
      float s = 0.f;
      for (int c = 0; c < 25; ++c) s += w3[((lay*25+m)*25+c)*3+tap] * b1[lay*25+c];
      v = a * s;
    } else if (k <= 27){                       // lf rows, e = k-26
      int e = k - 26;
      float s = 0.f;
      for (int c = 0; c < 25; ++c) s += w3[((lay*25+m)*25+c)*3+tap] * w1[(lay*25+c)*2+e];
      v = a * s;
    }
  }
  convA[idx] = f2bf(v);
}

// ---------------------------------------------------------------------------
// pass_kernel<PASS,CT>: per-wave stripe of (CT-2)*16 interior cols, halo 16.
// z-buffer (in-place, per wave): rows 0-24 = current y, 25 = valid, 26-27 = lf.
// PASS1: conv chain -> per-channel sums (gate numerator).
// PASS2: conv chain + fused gated proj GEMM reading B straight from z.
// ---------------------------------------------------------------------------
template<int PASS, int CT>
__global__ __launch_bounds__(256, (PASS==1) ? 4 : 2)
void pass_kernel(const float* __restrict__ lfg,
                 const float* __restrict__ w1g, const float* __restrict__ b1g,
                 const float* __restrict__ b3g,
                 const float* __restrict__ bng, const float* __restrict__ bnb,
                 const float* __restrict__ bnm, const float* __restrict__ bnv,
                 const u16* __restrict__ convA, const u16* __restrict__ Ab,
                 const float* __restrict__ pfb, const float* __restrict__ idb,
                 const float* __restrict__ fbg, const float* __restrict__ fbb,
                 const float* __restrict__ fbm, const float* __restrict__ fbv,
                 float* __restrict__ outpart)
{
  constexpr int IS   = (CT-2)*16;
  constexpr int CZ   = 16*CT + 2;
  constexpr int NBLK = 4096/(4*IS);

  __shared__ __align__(16) u16 zws[4][CZ*40];
  __shared__ __align__(16) float cAs[4][32];
  __shared__ __align__(16) float w4as[32], w4bs[32], c4s[32];
  __shared__ float accC[(PASS==1)?160:4];
  __shared__ __align__(16) float AfS[(PASS==2)?128:4], BfS[(PASS==2)?128:4];

  const int tid  = threadIdx.x;
  const int lane = tid & 63, wv = tid >> 6;
  const int q = lane >> 4, c16 = lane & 15;
  const int b = blockIdx.y, blk = blockIdx.x;
  const int stripe = blk*4 + wv;
  const int tbase  = stripe*IS - 16;

  // phase A: zero z buffers
  for (int x = tid; x < 4*CZ*20; x += 256) ((u32*)zws)[x] = 0u;
  __syncthreads();
  // phase B: valid-indicator row + constants
  for (int x = tid; x < 4*CZ; x += 256){
    int w = x / CZ, cz = x - w*CZ;
    int t = (blk*4 + w)*IS - 16 + cz - 1;
    zws[w][cz*40 + 25] = ((unsigned)t < 4096u) ? (u16)0x3F80 : (u16)0;
  }
  if (tid < 128){
    int i = tid >> 5, ch = tid & 31;
    float cc = 0.f;
    if (ch < 25){
      float a = bng[i*25+ch]*rsqrtf(bnv[i*25+ch]+1e-5f);
      cc = (b3g[i*25+ch] - bnm[i*25+ch])*a + bnb[i*25+ch];
    }
    cAs[i][ch] = cc;
  } else if (tid < 160){
    int ch = tid - 128;
    float wa=0.f, wb=0.f, cf=0.f;
    if (ch < 25){
      float a = bng[100+ch]*rsqrtf(bnv[100+ch]+1e-5f);
      wa = a*w1g[(100+ch)*2+0]; wb = a*w1g[(100+ch)*2+1];
      cf = a*b1g[100+ch] + (bnb[100+ch] - bnm[100+ch]*a);
    }
    w4as[ch]=wa; w4bs[ch]=wb; c4s[ch]=cf;
  }
  if constexpr (PASS==1){ if (tid < 160) accC[tid] = 0.f; }
  if constexpr (PASS==2){
    if (tid < 128){
      float fs=0.f, fsh=0.f;
      if (tid < 125){
        fs  = fbg[tid]*rsqrtf(fbv[tid]+1e-5f);
        fsh = (pfb[tid]+idb[tid]-fbm[tid])*fs + fbb[tid];
      }
      AfS[tid]=fs; BfS[tid]=fsh;
    }
  }
  __syncthreads();

  u16* z = zws[wv];

  f32x4 pacc[2][8];
  if constexpr (PASS==2){
    #pragma unroll
    for (int n2=0;n2<2;++n2)
      #pragma unroll
      for (int m2=0;m2<8;++m2) pacc[n2][m2] = (f32x4){0.f,0.f,0.f,0.f};
  }

  // ---------------- prologue: y4 = relu(folded 1x1), lf rows for layer 3 ----
  {
    float l8[CT], l9[CT], r0[CT], r1[CT];
    #pragma unroll
    for (int ct=0; ct<CT; ++ct){
      int t = tbase + 16*ct + c16;
      bool tk = (unsigned)t < 4096u;
      l8[ct] = tk ? lfg[(b*10+8)*4096 + t] : 0.f;
      l9[ct] = tk ? lfg[(b*10+9)*4096 + t] : 0.f;
      r0[ct] = 0.f; r1[ct] = 0.f;
      if (lane < 16 && tk){
        r0[ct] = lfg[(b*10+6)*4096 + t];
        r1[ct] = lfg[(b*10+7)*4096 + t];
      }
    }
    const f32x4 wa0 = *(const f32x4*)&w4as[4*q];
    const f32x4 wa1 = *(const f32x4*)&w4as[16+4*q];
    const f32x4 wb0 = *(const f32x4*)&w4bs[4*q];
    const f32x4 wb1 = *(const f32x4*)&w4bs[16+4*q];
    const f32x4 cf0 = *(const f32x4*)&c4s[4*q];
    const f32x4 cf1 = *(const f32x4*)&c4s[16+4*q];
    float s4[8];
    #pragma unroll
    for (int e=0;e<8;++e) s4[e] = 0.f;
    #pragma unroll
    for (int ct=0; ct<CT; ++ct){
      const int lc = 16*ct + c16;
      const int t  = tbase + lc;
      const bool tok   = (unsigned)t < 4096u;
      const bool inter = (ct >= 1) && (ct <= CT-2);
      float y0[4], y1[4];
      #pragma unroll
      for (int r=0;r<4;++r){
        float a = fmaxf(wa0[r]*l8[ct] + wb0[r]*l9[ct] + cf0[r], 0.f);
        float c = fmaxf(wa1[r]*l8[ct] + wb1[r]*l9[ct] + cf1[r], 0.f);
        y0[r] = tok ? a : 0.f;
        y1[r] = tok ? c : 0.f;
        if (PASS==1 && inter){ s4[r] += y0[r]; s4[4+r] += y1[r]; }
      }
      uint2 w0; w0.x = packbf2(y0[0],y0[1]); w0.y = packbf2(y0[2],y0[3]);
      *(uint2*)&z[(lc+1)*40 + 4*q] = w0;
      if (q < 2){
        uint2 w1_; w1_.x = packbf2(y1[0],y1[1]); w1_.y = packbf2(y1[2],y1[3]);
        *(uint2*)&z[(lc+1)*40 + 16 + 4*q] = w1_;
      } else if (q == 2){
        z[(lc+1)*40 + 24] = f2bf(y1[0]);
      }
      if (lane < 16)
        *(u32*)&z[(16*ct+lane+1)*40 + 26] = packbf2(r0[ct], r1[ct]);
    }
    if constexpr (PASS==1){
      #pragma unroll
      for (int e=0;e<8;++e){
        float v = s4[e];
        v += __shfl_xor(v,1); v += __shfl_xor(v,2); v += __shfl_xor(v,4); v += __shfl_xor(v,8);
        if (c16 == 0){
          int ch = (e>>2)*16 + 4*q + (e&3);
          if (ch < 25) atomicAdd(&accC[4*32+ch], v);
        }
      }
    }
  }

  if constexpr (PASS==2){
    { // GEMM kt=4 : B = y4 from z interior
      short8 Am[8];
      #pragma unroll
      for (int m2=0;m2<8;++m2)
        Am[m2] = *(const short8*)(Ab + b*24576 + ((4*8+m2)*64 + lane)*8);
      #pragma unroll
      for (int n2=0;n2<2;++n2){
        const short8 Bm = *(const short8*)&z[(17+16*n2+c16)*40 + 8*q];
        #pragma unroll
        for (int m2=0;m2<8;++m2)
          pacc[n2][m2] = __builtin_amdgcn_mfma_f32_16x16x32_bf16(Am[m2], Bm, pacc[n2][m2],0,0,0);
      }
    }
    { // GEMM kt=5 : identity, B built from lf global
      short8 Am[8];
      #pragma unroll
      for (int m2=0;m2<8;++m2)
        Am[m2] = *(const short8*)(Ab + b*24576 + ((5*8+m2)*64 + lane)*8);
      #pragma unroll
      for (int n2=0;n2<2;++n2){
        const int t = tbase + 16 + 16*n2 + c16;
        u32 bw[4];
        #pragma unroll
        for (int p=0;p<4;++p){
          int k0 = 8*q + 2*p;
          float v0 = (k0   < 10) ? lfg[(b*10+k0  )*4096 + t] : 0.f;
          float v1 = (k0+1 < 10) ? lfg[(b*10+k0+1)*4096 + t] : 0.f;
          bw[p] = packbf2(v0, v1);
        }
        const short8 Bm = __builtin_bit_cast(short8, bw);
        #pragma unroll
        for (int m2=0;m2<8;++m2)
          pacc[n2][m2] = __builtin_amdgcn_mfma_f32_16x16x32_bf16(Am[m2], Bm, pacc[n2][m2],0,0,0);
      }
    }
  }

  // ---------------- conv layers i = 3..0 (in-place, 2-deep prefetch) -------
  for (int i = 3; i >= 0; --i){
    short8 Ac0[3], Ac1[3];
    #pragma unroll
    for (int tp=0;tp<3;++tp){
      Ac0[tp] = *(const short8*)(convA + (((i*2+0)*3+tp)*64 + lane)*8);
      Ac1[tp] = *(const short8*)(convA + (((i*2+1)*3+tp)*64 + lane)*8);
    }
    const f32x4 cc0 = *(const f32x4*)&cAs[i][4*q];
    const f32x4 cc1 = *(const f32x4*)&cAs[i][16+4*q];
    short8 Ag[8];
    if constexpr (PASS==2){
      #pragma unroll
      for (int m2=0;m2<8;++m2)
        Ag[m2] = *(const short8*)(Ab + b*24576 + ((i*8+m2)*64 + lane)*8);
    }
    float r0[CT], r1[CT];
    #pragma unroll
    for (int ct=0;ct<CT;++ct){ r0[ct]=0.f; r1[ct]=0.f; }
    if (i > 0 && lane < 16){
      #pragma unroll
      for (int ct=0;ct<CT;++ct){
        int t = tbase + 16*ct + lane;
        if ((unsigned)t < 4096u){
          r0[ct] = lfg[(b*10 + 2*i-2)*4096 + t];
          r1[ct] = lfg[(b*10 + 2*i-1)*4096 + t];
        }
      }
    }
    float ysum[8];
    #pragma unroll
    for (int e=0;e<8;++e) ysum[e] = 0.f;

    short8 F0[3], F1[3], F2[3];
    {
      const u16* p = z + c16*40 + 8*q;
      F0[0] = *(const short8*)(p);
      F0[1] = *(const short8*)(p + 40);
      F0[2] = *(const short8*)(p + 80);
      const u16* p1 = z + (16 + c16)*40 + 8*q;
      F1[0] = *(const short8*)(p1);
      F1[1] = *(const short8*)(p1 + 40);
      F1[2] = *(const short8*)(p1 + 80);
    }
    #pragma unroll
    for (int ct=0; ct<CT; ++ct){
      short8* cur = (ct%3==0) ? F0 : ((ct%3==1) ? F1 : F2);
      short8* nx2 = (ct%3==0) ? F2 : ((ct%3==1) ? F0 : F1);
      if (ct < CT-2){
        const u16* p = z + (16*(ct+2) + c16)*40 + 8*q;
        nx2[0] = *(const short8*)(p);
        nx2[1] = *(const short8*)(p + 40);
        nx2[2] = *(const short8*)(p + 80);
      }
      __builtin_amdgcn_sched_barrier(0);   // reads above, writes below
      f32x4 a0 = {0.f,0.f,0.f,0.f}, a1 = {0.f,0.f,0.f,0.f};
      #pragma unroll
      for (int tp=0;tp<3;++tp){
        a0 = __builtin_amdgcn_mfma_f32_16x16x32_bf16(Ac0[tp], cur[tp], a0, 0,0,0);
        a1 = __builtin_amdgcn_mfma_f32_16x16x32_bf16(Ac1[tp], cur[tp], a1, 0,0,0);
      }
      const int lc = 16*ct + c16;
      const int t  = tbase + lc;
      const bool tok   = (unsigned)t < 4096u;
      const bool inter = (ct >= 1) && (ct <= CT-2);
      float y0[4], y1[4];
      #pragma unroll
      for (int r=0;r<4;++r){
        float u0 = fmaxf(a0[r] + cc0[r], 0.f);
        float u1 = fmaxf(a1[r] + cc1[r], 0.f);
        y0[r] = tok ? u0 : 0.f;
        y1[r] = tok ? u1 : 0.f;
        if (PASS==1 && inter){ ysum[r] += y0[r]; ysum[4+r] += y1[r]; }
      }
      if (i > 0 || PASS==2){
        uint2 w0; w0.x = packbf2(y0[0],y0[1]); w0.y = packbf2(y0[2],y0[3]);
        *(uint2*)&z[(lc+1)*40 + 4*q] = w0;
        if (q < 2){
          uint2 w1_; w1_.x = packbf2(y1[0],y1[1]); w1_.y = packbf2(y1[2],y1[3]);
          *(uint2*)&z[(lc+1)*40 + 16 + 4*q] = w1_;
        } else if (q == 2){
          z[(lc+1)*40 + 24] = f2bf(y1[0]);
        }
      }
      if (i > 0 && lane < 16)
        *(u32*)&z[(16*ct+lane+1)*40 + 26] = packbf2(r0[ct], r1[ct]);
    }
    if constexpr (PASS==1){
      #pragma unroll
      for (int e=0;e<8;++e){
        float v = ysum[e];
        v += __shfl_xor(v,1); v += __shfl_xor(v,2); v += __shfl_xor(v,4); v += __shfl_xor(v,8);
        if (c16 == 0){
          int ch = (e>>2)*16 + 4*q + (e&3);
          if (ch < 25) atomicAdd(&accC[i*32+ch], v);
        }
      }
    }
    if constexpr (PASS==2){                 // GEMM kt=i : B = y_i from z
      #pragma unroll
      for (int n2=0;n2<2;++n2){
        const short8 Bm = *(const short8*)&z[(17+16*n2+c16)*40 + 8*q];
        #pragma unroll
        for (int m2=0;m2<8;++m2)
          pacc[n2][m2] = __builtin_amdgcn_mfma_f32_16x16x32_bf16(Ag[m2], Bm, pacc[n2][m2],0,0,0);
      }
    }
  }

  if constexpr (PASS==1){
    __syncthreads();
    if (tid < 160) outpart[(b*NBLK + blk)*160 + tid] = accC[tid];
  }
  if constexpr (PASS==2){
    f32x4 ps[8];
    #pragma unroll
    for (int m2=0;m2<8;++m2){
      const f32x4 af = *(const f32x4*)&AfS[m2*16+4*q];
      const f32x4 bf = *(const f32x4*)&BfS[m2*16+4*q];
      #pragma unroll
      for (int r=0;r<4;++r){
        float s = fmaxf(pacc[0][m2][r]*af[r] + bf[r], 0.f)
                + fmaxf(pacc[1][m2][r]*af[r] + bf[r], 0.f);
        s += __shfl_xor(s,1); s += __shfl_xor(s,2); s += __shfl_xor(s,4); s += __shfl_xor(s,8);
        ps[m2][r] = s;
      }
    }
    if (c16 == 0){
      const int widx = (b*NBLK + blk)*4 + wv;
      #pragma unroll
      for (int m2=0;m2<8;++m2)
        *(f32x4*)&outpart[widx*128 + m2*16 + 4*q] = ps[m2];
    }
  }
}

// ---------------------------------------------------------------------------
// K2: gating MLP + per-batch gated proj A-fragments (kt 0-4 gated, kt 5 id)
// ---------------------------------------------------------------------------
__global__ void gate_kernel(const float* __restrict__ partialC,
                            const float* __restrict__ gw1, const float* __restrict__ gb1,
                            const float* __restrict__ gw2, const float* __restrict__ gb2,
                            const float* __restrict__ pf_w, const float* __restrict__ id_w,
                            u16* __restrict__ Ab)
{
  int b = blockIdx.x, tid = threadIdx.x;
  __shared__ float avg[125], h1[31], g[6];
  if (tid < 160){
    float s = 0.f;
    for (int k = 0; k < 16; ++k) s += partialC[(b*16+k)*160 + tid];
    int sc = tid >> 5, ch = tid & 31;
    if (ch < 25) avg[sc*25+ch] = s * (1.f/4096.f);
  }
  __syncthreads();
  if (tid < 31){
    float s = gb1[tid];
    for (int c = 0; c < 125; ++c) s += avg[c] * gw1[tid*125 + c];
    h1[tid] = fmaxf(s, 0.f);
  }
  __syncthreads();
  if (tid < 5){
    float s = gb2[tid];
    for (int j = 0; j < 31; ++j) s += h1[j] * gw2[tid*31 + j];
    g[tid] = 1.f / (1.f + expf(-s));
  }
  if (tid == 5) g[5] = 1.f;
  __syncthreads();
  for (int idx = tid; idx < 24576; idx += 256){
    int j = idx & 7, l = (idx>>3) & 63, mt = (idx>>9) & 7, kt = idx >> 12;
    int m = mt*16 + (l & 15), k = (l>>4)*8 + j;
    float v = 0.f;
    if (m < 125){
      if (kt < 5){ if (k < 25) v = pf_w[m*125 + kt*25 + k] * g[kt]; }
      else       { if (k < 10) v = id_w[m*10 + k]; }
    }
    Ab[b*24576 + idx] = f2bf(v);
  }
}

// ---------------------------------------------------------------------------
// K4: pooled mean -> LayerNorm -> fc1 + LeakyReLU(0.2) -> fc2
// ---------------------------------------------------------------------------
__global__ void final_kernel(const float* __restrict__ pooledpart,
                             const float* __restrict__ ln_g, const float* __restrict__ ln_b,
                             const float* __restrict__ fc1_w, const float* __restrict__ fc1_b,
                             const float* __restrict__ fc2_w, const float* __restrict__ fc2_b,
                             float* __restrict__ out)
{
  int b = blockIdx.x, tid = threadIdx.x;
  __shared__ float pl[125], nr[125], hh[64], st[2];
  for (int c = tid; c < 125; c += 64){
    float s = 0.f;
    for (int k = 0; k < 128; ++k) s += pooledpart[(b*128+k)*128 + c];
    pl[c] = s * (1.f/4096.f);
  }
  __syncthreads();
  if (tid == 0){
    float mu = 0.f;
    for (int c = 0; c < 125; ++c) mu += pl[c];
    mu /= 125.f;
    float va = 0.f;
    for (int c = 0; c < 125; ++c){ float d = pl[c] - mu; va += d*d; }
    va /= 125.f;
    st[0] = mu; st[1] = rsqrtf(va + 1e-5f);
  }
  __syncthreads();
  for (int c = tid; c < 125; c += 64)
    nr[c] = (pl[c] - st[0]) * st[1] * ln_g[c] + ln_b[c];
  __syncthreads();
  {
    float s = fc1_b[tid];
    for (int c = 0; c < 125; ++c) s += nr[c] * fc1_w[tid*125 + c];
    hh[tid] = (s > 0.f) ? s : 0.2f * s;
  }
  __syncthreads();
  if (tid < 2){
    float s = fc2_b[tid];
    for (int j = 0; j < 64; ++j) s += hh[j] * fc2_w[tid*64 + j];
    out[b*2 + tid] = s;
  }
}

// ---------------------------------------------------------------------------
extern "C" void kernel_launch(void* const* d_in, const int* in_sizes, int n_in,
                              void* d_out, int out_size, void* d_ws, size_t ws_size,
                              hipStream_t stream)
{
  const float* lf    = (const float*)d_in[0];
  const float* w1    = (const float*)d_in[1];
  const float* b1    = (const float*)d_in[2];
  const float* w3    = (const float*)d_in[3];
  const float* b3    = (const float*)d_in[4];
  const float* bn_g  = (const float*)d_in[5];
  const float* bn_b  = (const float*)d_in[6];
  const float* bn_m  = (const float*)d_in[7];
  const float* bn_v  = (const float*)d_in[8];
  const float* gw1   = (const float*)d_in[9];
  const float* gb1   = (const float*)d_in[10];
  const float* gw2   = (const float*)d_in[11];
  const float* gb2   = (const float*)d_in[12];
  const float* id_w  = (const float*)d_in[13];
  const float* id_b  = (const float*)d_in[14];
  const float* pf_w  = (const float*)d_in[15];
  const float* pf_b  = (const float*)d_in[16];
  const float* fbn_g = (const float*)d_in[17];
  const float* fbn_b = (const float*)d_in[18];
  const float* fbn_m = (const float*)d_in[19];
  const float* fbn_v = (const float*)d_in[20];
  const float* ln_g  = (const float*)d_in[21];
  const float* ln_b  = (const float*)d_in[22];
  const float* fc1_w = (const float*)d_in[23];
  const float* fc1_b = (const float*)d_in[24];
  const float* fc2_w = (const float*)d_in[25];
  const float* fc2_b = (const float*)d_in[26];

  char* ws = (char*)d_ws;
  float* partialC   = (float*)ws;                                  // 1,310,720 B
  float* pooledpart = (float*)(ws + 1310720);                      // 8,388,608 B
  u16*   Ab         = (u16*)(ws + 1310720 + 8388608);              // 6,291,456 B
  u16*   convA      = (u16*)(ws + 1310720 + 8388608 + 6291456);    //    24,576 B

  prep_kernel<<<48, 256, 0, stream>>>(w3, w1, b1, bn_g, bn_v, convA);
  pass_kernel<1,6><<<dim3(16,128), 256, 0, stream>>>(lf, w1, b1, b3, bn_g, bn_b,
      bn_m, bn_v, convA, Ab, pf_b, id_b, fbn_g, fbn_b, fbn_m, fbn_v, partialC);
  gate_kernel<<<128, 256, 0, stream>>>(partialC, gw1, gb1, gw2, gb2, pf_w, id_w, Ab);
  pass_kernel<2,4><<<dim3(32,128), 256, 0, stream>>>(lf, w1, b1, b3, bn_g, bn_b,
      bn_m, bn_v, convA, Ab, pf_b, id_b, fbn_g, fbn_b, fbn_m, fbn_v, pooledpart);
  final_kernel<<<128, 64, 0, stream>>>(pooledpart, ln_g, ln_b, fc1_w, fc1_b,
      fc2_w, fc2_b, (float*)d_out);
}